// Round 2
// baseline (1152.500 us; speedup 1.0000x reference)
//
#include <hip/hip_runtime.h>
#include <cstdint>
#include <cstddef>

// Problem constants
#define L_  4096   // H*W = 64*64
#define C_  256    // IN_DIM
#define NH  8      // heads
#define KK  288    // KEY_DIM*K*K = 32*9
#define MM  256    // MEM_DIM
#define DD  64     // HEAD_DIM
#define HC  512    // NH*DD
#define OD  256    // OUT_DIM

// ---------------------------------------------------------------------------
// Transpose W_proj (256x256 -> Wpt[c][o]) and W_out (256x512 -> Wot[m][o])
// so GEMM kernels can read weight columns as coalesced float4s.
// grid: 512 blocks x 256 threads. blocks [0,256): W_proj rows; [256,512): W_out rows.
// ---------------------------------------------------------------------------
__global__ __launch_bounds__(256) void k_transpose(
    const float* __restrict__ Wp, const float* __restrict__ Wo,
    float* __restrict__ Wpt, float* __restrict__ Wot) {
  const int t = threadIdx.x;
  const int bid = blockIdx.x;
  if (bid < 256) {
    const int o = bid;
    Wpt[t * 256 + o] = Wp[o * 256 + t];
  } else {
    const int o = bid - 256;
    Wot[t * 256 + o]         = Wo[o * 512 + t];
    Wot[(t + 256) * 256 + o] = Wo[o * 512 + t + 256];
  }
}

// ---------------------------------------------------------------------------
// 1x1 conv projection: proj[b][o][l] = sum_c W_proj[o][c] * x[b][c][l] + b_proj[o]
// Block: 256 threads, tile = 64 pixels x 256 outputs. LDS stages x tile (64KB).
// Thread tile: 4 outputs x 16 pixels. grid: (L/64, B)
// ---------------------------------------------------------------------------
__global__ __launch_bounds__(256) void k_proj(
    const float* __restrict__ x, const float* __restrict__ Wpt,
    const float* __restrict__ bp, float* __restrict__ proj) {
  __shared__ float xs[C_ * 64];  // 64 KB
  const int t  = threadIdx.x;
  const int b  = blockIdx.y;
  const int l0 = blockIdx.x * 64;
  const float* xb = x + (size_t)b * C_ * L_ + l0;
#pragma unroll 8
  for (int k = 0; k < 64; ++k) {
    const int idx = t + k * 256;
    xs[idx] = xb[(idx >> 6) * L_ + (idx & 63)];
  }
  __syncthreads();

  const int o0 = (t & 63) * 4;   // 64 o-groups x 4
  const int p0 = (t >> 6) * 16;  // 4 p-groups x 16

  float acc[4][16];
#pragma unroll
  for (int j = 0; j < 4; ++j)
#pragma unroll
    for (int i = 0; i < 16; ++i) acc[j][i] = 0.f;

  for (int c = 0; c < C_; ++c) {
    const float4 w = *(const float4*)(Wpt + c * 256 + o0);
    const float* xr = xs + c * 64 + p0;
    float xv[16];
#pragma unroll
    for (int i = 0; i < 16; i += 4) {
      const float4 xq = *(const float4*)(xr + i);
      xv[i] = xq.x; xv[i + 1] = xq.y; xv[i + 2] = xq.z; xv[i + 3] = xq.w;
    }
#pragma unroll
    for (int i = 0; i < 16; ++i) {
      acc[0][i] = fmaf(w.x, xv[i], acc[0][i]);
      acc[1][i] = fmaf(w.y, xv[i], acc[1][i]);
      acc[2][i] = fmaf(w.z, xv[i], acc[2][i]);
      acc[3][i] = fmaf(w.w, xv[i], acc[3][i]);
    }
  }

#pragma unroll
  for (int j = 0; j < 4; ++j) {
    const float bias = bp[o0 + j];
    float* pr = proj + ((size_t)b * C_ + o0 + j) * L_ + l0 + p0;
#pragma unroll
    for (int i = 0; i < 16; i += 4) {
      float4 r;
      r.x = acc[j][i]     + bias;
      r.y = acc[j][i + 1] + bias;
      r.z = acc[j][i + 2] + bias;
      r.w = acc[j][i + 3] + bias;
      *(float4*)(pr + i) = r;
    }
  }
}

// ---------------------------------------------------------------------------
// Fused attention per (batch, head, 32-pixel tile):
//   q[a][px] = proj[b][c][(y+dy)*64 + x+dx]  with (c,p) from a*8+n = c*9+p, zero-pad OOB
//   logits[i][px] = sum_a key_bank[n][a][i] * q[a][px]   (i in [0,256))
//   att = softmax over i
//   heads[z][n*64+d][l] = sum_i memory_bank[n][i][d] * att[i][px]
// Block: 256 threads. LDS: q tile 288x32 f32 (36 KB), reused for att (256x32).
// grid: (L/32, NH, NB). Global batch = b0 + blockIdx.z; heads indexed by blockIdx.z.
// ---------------------------------------------------------------------------
__global__ __launch_bounds__(256) void k_attn(
    const float* __restrict__ proj, const float* __restrict__ keyb,
    const float* __restrict__ memb, float* __restrict__ heads, int b0) {
  __shared__ float qs[KK * 32];  // 36864 B; att aliases first 256*32
  const int t  = threadIdx.x;
  const int l0 = blockIdx.x * 32;
  const int n  = blockIdx.y;
  const int z  = blockIdx.z;
  const int b  = b0 + z;
  const int y  = l0 >> 6;
  const int x0 = l0 & 63;
  const float* pb = proj + (size_t)b * C_ * L_;

  // Phase A: unfold into LDS
  for (int it = 0; it < 36; ++it) {
    const int idx = t + it * 256;
    const int a   = idx >> 5;
    const int px  = idx & 31;
    const unsigned g = (unsigned)a * 8u + (unsigned)n;
    const unsigned c = g / 9u;
    const unsigned p = g - c * 9u;
    const int dy = (int)(p / 3u) - 1;
    const int dx = (int)(p % 3u) - 1;
    const int yy = y + dy;
    const int xx = x0 + px + dx;
    float v = 0.f;
    if ((unsigned)yy < 64u && (unsigned)xx < 64u)
      v = pb[(size_t)c * L_ + yy * 64 + xx];
    qs[a * 32 + px] = v;
  }
  __syncthreads();

  // Phase B: logits, thread tile 8i x 4p
  const int ig = t & 31;        // 32 i-groups x 8
  const int pg = t >> 5;        // 8 p-groups x 4
  const int i0 = ig * 8;
  const int p0 = pg * 4;

  float acc[8][4];
#pragma unroll
  for (int ii = 0; ii < 8; ++ii)
#pragma unroll
    for (int pp = 0; pp < 4; ++pp) acc[ii][pp] = 0.f;

  const float* kb = keyb + (size_t)n * KK * MM + i0;
#pragma unroll 2
  for (int a = 0; a < KK; ++a) {
    const float4 k0 = *(const float4*)(kb + (size_t)a * MM);
    const float4 k1 = *(const float4*)(kb + (size_t)a * MM + 4);
    const float4 qv = *(const float4*)(qs + a * 32 + p0);
    const float kv[8] = {k0.x, k0.y, k0.z, k0.w, k1.x, k1.y, k1.z, k1.w};
    const float qa[4] = {qv.x, qv.y, qv.z, qv.w};
#pragma unroll
    for (int ii = 0; ii < 8; ++ii)
#pragma unroll
      for (int pp = 0; pp < 4; ++pp)
        acc[ii][pp] = fmaf(kv[ii], qa[pp], acc[ii][pp]);
  }

  // Phase C: softmax over i (reduce across the 32 ig-lanes sharing a pixel)
  float att[8][4];
#pragma unroll
  for (int pp = 0; pp < 4; ++pp) {
    float m = acc[0][pp];
#pragma unroll
    for (int ii = 1; ii < 8; ++ii) m = fmaxf(m, acc[ii][pp]);
#pragma unroll
    for (int msk = 16; msk >= 1; msk >>= 1) m = fmaxf(m, __shfl_xor(m, msk, 64));
    float s = 0.f;
#pragma unroll
    for (int ii = 0; ii < 8; ++ii) {
      const float e = __expf(acc[ii][pp] - m);
      att[ii][pp] = e;
      s += e;
    }
#pragma unroll
    for (int msk = 16; msk >= 1; msk >>= 1) s += __shfl_xor(s, msk, 64);
    const float inv = 1.f / s;
#pragma unroll
    for (int ii = 0; ii < 8; ++ii) att[ii][pp] *= inv;
  }

  __syncthreads();  // all q reads done before overwrite
#pragma unroll
  for (int ii = 0; ii < 8; ++ii)
#pragma unroll
    for (int pp = 0; pp < 4; ++pp)
      qs[(i0 + ii) * 32 + p0 + pp] = att[ii][pp];
  __syncthreads();

  // Phase D: PV, thread tile 2d x 4p
  const int dg  = t & 31;   // 32 d-groups x 2
  const int pg2 = t >> 5;   // 8 p-groups x 4
  const int d0  = dg * 2;
  const int pp0 = pg2 * 4;
  float a0[4] = {0.f, 0.f, 0.f, 0.f};
  float a1[4] = {0.f, 0.f, 0.f, 0.f};
  const float* mb = memb + (size_t)n * MM * DD + d0;
#pragma unroll 4
  for (int i = 0; i < MM; ++i) {
    const float2 mv = *(const float2*)(mb + (size_t)i * DD);
    const float4 av = *(const float4*)(qs + i * 32 + pp0);
    a0[0] = fmaf(mv.x, av.x, a0[0]);
    a0[1] = fmaf(mv.x, av.y, a0[1]);
    a0[2] = fmaf(mv.x, av.z, a0[2]);
    a0[3] = fmaf(mv.x, av.w, a0[3]);
    a1[0] = fmaf(mv.y, av.x, a1[0]);
    a1[1] = fmaf(mv.y, av.y, a1[1]);
    a1[2] = fmaf(mv.y, av.z, a1[2]);
    a1[3] = fmaf(mv.y, av.w, a1[3]);
  }
  float* hb = heads + ((size_t)z * HC + n * DD + d0) * L_ + l0 + pp0;
  *(float4*)(hb)      = make_float4(a0[0], a0[1], a0[2], a0[3]);
  *(float4*)(hb + L_) = make_float4(a1[0], a1[1], a1[2], a1[3]);
}

// ---------------------------------------------------------------------------
// Final 1x1 conv: out[b][o][l] = sum_m W_out[o][m] * heads[z][m][l] + b_out[o]
// Block: 256 threads, tile = 32 pixels x 128 outputs (o split in halves).
// Thread tile: 4 outputs x 4 pixels. grid: (L/32, 2, NB). Stage hs tile (64KB).
// ---------------------------------------------------------------------------
__global__ __launch_bounds__(256) void k_out(
    const float* __restrict__ heads, const float* __restrict__ Wot,
    const float* __restrict__ bo, float* __restrict__ out, int b0) {
  __shared__ float hs[HC * 32];  // 64 KB
  const int t  = threadIdx.x;
  const int oh = blockIdx.y;
  const int z  = blockIdx.z;
  const int b  = b0 + z;
  const int l0 = blockIdx.x * 32;
  const float* hb = heads + (size_t)z * HC * L_ + l0;
#pragma unroll 8
  for (int k = 0; k < 64; ++k) {
    const int idx = t + k * 256;
    hs[idx] = hb[(idx >> 5) * L_ + (idx & 31)];
  }
  __syncthreads();

  const int o0 = oh * 128 + (t & 31) * 4;  // 32 o-groups x 4 per half
  const int p0 = (t >> 5) * 4;             // 8 p-groups x 4

  float acc[4][4];
#pragma unroll
  for (int j = 0; j < 4; ++j)
#pragma unroll
    for (int pp = 0; pp < 4; ++pp) acc[j][pp] = 0.f;

#pragma unroll 4
  for (int m = 0; m < HC; ++m) {
    const float4 w = *(const float4*)(Wot + m * 256 + o0);
    const float4 hv = *(const float4*)(hs + m * 32 + p0);
    const float wv[4] = {w.x, w.y, w.z, w.w};
    const float ha[4] = {hv.x, hv.y, hv.z, hv.w};
#pragma unroll
    for (int j = 0; j < 4; ++j)
#pragma unroll
      for (int pp = 0; pp < 4; ++pp)
        acc[j][pp] = fmaf(wv[j], ha[pp], acc[j][pp]);
  }

#pragma unroll
  for (int j = 0; j < 4; ++j) {
    const float bias = bo[o0 + j];
    float4 r;
    r.x = acc[j][0] + bias;
    r.y = acc[j][1] + bias;
    r.z = acc[j][2] + bias;
    r.w = acc[j][3] + bias;
    *(float4*)(out + ((size_t)b * OD + o0 + j) * L_ + l0 + p0) = r;
  }
}

// ---------------------------------------------------------------------------
extern "C" void kernel_launch(void* const* d_in, const int* in_sizes, int n_in,
                              void* d_out, int out_size, void* d_ws, size_t ws_size,
                              hipStream_t stream) {
  const float* x    = (const float*)d_in[0];
  const float* Wp   = (const float*)d_in[1];
  const float* bp   = (const float*)d_in[2];
  const float* keyb = (const float*)d_in[3];
  const float* memb = (const float*)d_in[4];
  const float* Wo   = (const float*)d_in[5];
  const float* bo   = (const float*)d_in[6];
  float* out = (float*)d_out;

  // Workspace layout: Wpt (256 KB) | Wot (512 KB) | heads (8 or 64 MB)
  const size_t WPT_B   = (size_t)C_ * 256 * 4;           // 262144
  const size_t WOT_B   = (size_t)HC * 256 * 4;           // 524288
  const size_t HB1_B   = (size_t)HC * L_ * 4;            // 8 MB per batch
  char* ws = (char*)d_ws;
  float* Wpt   = (float*)ws;
  float* Wot   = (float*)(ws + WPT_B);
  float* heads = (float*)(ws + WPT_B + WOT_B);

  // proj scratch lives in d_out (exactly 8*256*4096 floats); each batch's
  // region is consumed by k_attn before k_out overwrites it with the result.
  float* proj = out;

  hipLaunchKernelGGL(k_transpose, dim3(512),   dim3(256), 0, stream, Wp, Wo, Wpt, Wot);
  hipLaunchKernelGGL(k_proj,      dim3(64, 8), dim3(256), 0, stream, x, Wpt, bp, proj);

  if (ws_size >= WPT_B + WOT_B + 8 * HB1_B) {
    // Full-batch schedule: one attn launch, one out launch.
    hipLaunchKernelGGL(k_attn, dim3(128, 8, 8), dim3(256), 0, stream,
                       proj, keyb, memb, heads, 0);
    hipLaunchKernelGGL(k_out,  dim3(128, 2, 8), dim3(256), 0, stream,
                       heads, Wot, bo, out, 0);
  } else {
    // Per-batch pipeline: heads buffer holds one batch (8 MB).
    // k_attn(b) reads proj[b] (in d_out), k_out(b) overwrites that region.
    // The 3x3 unfold is spatial-only, so batches are independent.
    for (int b = 0; b < 8; ++b) {
      hipLaunchKernelGGL(k_attn, dim3(128, 8, 1), dim3(256), 0, stream,
                         proj, keyb, memb, heads, b);
      hipLaunchKernelGGL(k_out,  dim3(128, 2, 1), dim3(256), 0, stream,
                         heads, Wot, bo, out, b);
    }
  }
}

// Round 3
// 541.696 us; speedup vs baseline: 2.1276x; 2.1276x over previous
//
#include <hip/hip_runtime.h>
#include <cstdint>
#include <cstddef>

// Problem constants
#define L_  4096   // H*W = 64*64
#define C_  256    // IN_DIM
#define NH  8      // heads
#define KK  288    // KEY_DIM*K*K = 32*9
#define MM  256    // MEM_DIM
#define DD  64     // HEAD_DIM
#define HC  512    // NH*DD
#define OD  256    // OUT_DIM
#define QSTR 296   // LDS row stride (bf16 elems): 592 B, 16B-aligned, ~2-way banks

typedef unsigned short u16;
typedef __attribute__((ext_vector_type(8))) short bf8;    // 8 bf16 = 4 VGPRs
typedef __attribute__((ext_vector_type(4))) float f32x4;  // MFMA C/D

static __device__ __forceinline__ u16 f2bf(float f) {
  union { float f; unsigned u; } v; v.f = f;
  const unsigned r = v.u + 0x7FFFu + ((v.u >> 16) & 1u);
  return (u16)(r >> 16);
}

// ---------------------------------------------------------------------------
// Transpose W_proj (256x256 -> Wpt[c][o]) and W_out (256x512 -> Wot[m][o]).
// ---------------------------------------------------------------------------
__global__ __launch_bounds__(256) void k_transpose(
    const float* __restrict__ Wp, const float* __restrict__ Wo,
    float* __restrict__ Wpt, float* __restrict__ Wot) {
  const int t = threadIdx.x;
  const int bid = blockIdx.x;
  if (bid < 256) {
    const int o = bid;
    Wpt[t * 256 + o] = Wp[o * 256 + t];
  } else {
    const int o = bid - 256;
    Wot[t * 256 + o]         = Wo[o * 512 + t];
    Wot[(t + 256) * 256 + o] = Wo[o * 512 + t + 256];
  }
}

// ---------------------------------------------------------------------------
// Prep: key_bank [n][a][i] f32 -> Ktb [n][i][a] bf16 (A-fragment friendly)
//       memory_bank [n][i][d] f32 -> memt [n][d][i] bf16
// grid: 2304 + 2048 blocks x 256 threads.
// ---------------------------------------------------------------------------
__global__ __launch_bounds__(256) void k_prep(
    const float* __restrict__ keyb, const float* __restrict__ memb,
    u16* __restrict__ Ktb, u16* __restrict__ memt) {
  const int t = threadIdx.x;
  const int bid = blockIdx.x;
  if (bid < 2304) {
    const int nh = bid / 288, a = bid - nh * 288;
    const float v = keyb[((size_t)nh * 288 + a) * 256 + t];
    Ktb[(size_t)nh * (256 * 288) + (size_t)t * 288 + a] = f2bf(v);
  } else {
    const int q = bid - 2304;           // 0..2047
    const int nh = q >> 8, i = q & 255;
    if (t < 64) {
      const float v = memb[((size_t)nh * 256 + i) * 64 + t];
      memt[(size_t)nh * (64 * 256) + (size_t)t * 256 + i] = f2bf(v);
    }
  }
}

// ---------------------------------------------------------------------------
// 1x1 conv projection (fp32 VALU): proj[b][o][l] = W_proj x + b. Unchanged.
// ---------------------------------------------------------------------------
__global__ __launch_bounds__(256) void k_proj(
    const float* __restrict__ x, const float* __restrict__ Wpt,
    const float* __restrict__ bp, float* __restrict__ proj) {
  __shared__ float xs[C_ * 64];  // 64 KB
  const int t  = threadIdx.x;
  const int b  = blockIdx.y;
  const int l0 = blockIdx.x * 64;
  const float* xb = x + (size_t)b * C_ * L_ + l0;
#pragma unroll 8
  for (int k = 0; k < 64; ++k) {
    const int idx = t + k * 256;
    xs[idx] = xb[(idx >> 6) * L_ + (idx & 63)];
  }
  __syncthreads();

  const int o0 = (t & 63) * 4;
  const int p0 = (t >> 6) * 16;

  float acc[4][16];
#pragma unroll
  for (int j = 0; j < 4; ++j)
#pragma unroll
    for (int i = 0; i < 16; ++i) acc[j][i] = 0.f;

  for (int c = 0; c < C_; ++c) {
    const float4 w = *(const float4*)(Wpt + c * 256 + o0);
    const float* xr = xs + c * 64 + p0;
    float xv[16];
#pragma unroll
    for (int i = 0; i < 16; i += 4) {
      const float4 xq = *(const float4*)(xr + i);
      xv[i] = xq.x; xv[i + 1] = xq.y; xv[i + 2] = xq.z; xv[i + 3] = xq.w;
    }
#pragma unroll
    for (int i = 0; i < 16; ++i) {
      acc[0][i] = fmaf(w.x, xv[i], acc[0][i]);
      acc[1][i] = fmaf(w.y, xv[i], acc[1][i]);
      acc[2][i] = fmaf(w.z, xv[i], acc[2][i]);
      acc[3][i] = fmaf(w.w, xv[i], acc[3][i]);
    }
  }

#pragma unroll
  for (int j = 0; j < 4; ++j) {
    const float bias = bp[o0 + j];
    float* pr = proj + ((size_t)b * C_ + o0 + j) * L_ + l0 + p0;
#pragma unroll
    for (int i = 0; i < 16; i += 4) {
      float4 r;
      r.x = acc[j][i]     + bias;
      r.y = acc[j][i + 1] + bias;
      r.z = acc[j][i + 2] + bias;
      r.w = acc[j][i + 3] + bias;
      *(float4*)(pr + i) = r;
    }
  }
}

// ---------------------------------------------------------------------------
// MFMA fused attention per (batch, head, 64-px row tile). 4 waves.
//  Phase A: unfold proj -> bf16 LDS qs[px][a] (stride QSTR)
//  Phase B: logits = Ktb[n] (A, 256x288) x qs (B, 288x64), per-wave 64i x 64px
//           -> acc[n'][m] f32x4 ; i = w*64+16m+4g+r, px = 16n'+c (c=lane&15,g=lane>>4)
//  Phase C: softmax over i (in-lane 16 + shfl_xor 16/32 + 4-wave LDS combine)
//           att -> bf16 back into qs[px][i]
//  Phase D: PV = memt[n] (A, 64x256) x att (B, 256x64); wave w handles px0=16w
//  heads fp32 [z][n*64+d][l]
// ---------------------------------------------------------------------------
__global__ __launch_bounds__(256) void k_attn_mfma(
    const float* __restrict__ proj, const u16* __restrict__ Ktb,
    const u16* __restrict__ memt, float* __restrict__ heads, int b0) {
  __shared__ __align__(16) u16 qs[64 * QSTR];  // 37,888 B
  __shared__ float wred[512];                  // [0:256) wave-max, [256:512) wave-sum
  const int t    = threadIdx.x;
  const int w    = t >> 6;
  const int lane = t & 63;
  const int c    = lane & 15;
  const int g    = lane >> 4;
  const int n    = blockIdx.y;
  const int z    = blockIdx.z;
  const int b    = b0 + z;
  const int y    = blockIdx.x;        // 64-px tile == one image row
  const int l0   = y * 64;
  const float* pb = proj + (size_t)b * C_ * L_;

  // ---- Phase A: unfold -> bf16 LDS, pair-packed u32 writes
  for (int it = 0; it < 36; ++it) {
    const int idx = t + it * 256;     // 0..9215
    const int a2  = idx >> 6;         // 0..143
    const int px  = idx & 63;
    unsigned pk = 0;
#pragma unroll
    for (int e = 0; e < 2; ++e) {
      const int a = a2 * 2 + e;
      const unsigned gg = (unsigned)a * 8u + (unsigned)n;
      const unsigned cc = gg / 9u;
      const unsigned p  = gg - cc * 9u;
      const int dy = (int)(p / 3u) - 1;
      const int dx = (int)(p % 3u) - 1;
      const int yy = y + dy;
      const int xx = px + dx;
      float v = 0.f;
      if ((unsigned)yy < 64u && (unsigned)xx < 64u)
        v = pb[(size_t)cc * L_ + yy * 64 + xx];
      pk |= (unsigned)f2bf(v) << (16 * e);
    }
    *(unsigned*)(&qs[px * QSTR + a2 * 2]) = pk;
  }
  __syncthreads();

  // ---- Phase B: logits
  f32x4 acc[4][4];                    // [n'][m]
#pragma unroll
  for (int nn = 0; nn < 4; ++nn)
#pragma unroll
    for (int m = 0; m < 4; ++m) acc[nn][m] = (f32x4){0.f, 0.f, 0.f, 0.f};

  const u16* kb = Ktb + (size_t)n * (256 * 288);
  for (int ks = 0; ks < 9; ++ks) {
    const int k0 = ks * 32;
    bf8 bfr[4];
#pragma unroll
    for (int nn = 0; nn < 4; ++nn)
      bfr[nn] = *(const bf8*)(&qs[(nn * 16 + c) * QSTR + k0 + g * 8]);
#pragma unroll
    for (int m = 0; m < 4; ++m) {
      const bf8 afr = *(const bf8*)(kb + (size_t)(w * 64 + m * 16 + c) * 288 + k0 + g * 8);
#pragma unroll
      for (int nn = 0; nn < 4; ++nn)
        acc[nn][m] = __builtin_amdgcn_mfma_f32_16x16x32_bf16(afr, bfr[nn], acc[nn][m], 0, 0, 0);
    }
  }

  // ---- Phase C: softmax over i (256 rows spread across 4 waves)
#pragma unroll
  for (int nn = 0; nn < 4; ++nn) {
    float m0 = acc[nn][0][0];
#pragma unroll
    for (int m = 0; m < 4; ++m)
#pragma unroll
      for (int r = 0; r < 4; ++r) m0 = fmaxf(m0, acc[nn][m][r]);
    m0 = fmaxf(m0, __shfl_xor(m0, 16, 64));
    m0 = fmaxf(m0, __shfl_xor(m0, 32, 64));
    if (g == 0) wred[w * 64 + nn * 16 + c] = m0;
  }
  __syncthreads();
  float inv_s[4];
#pragma unroll
  for (int nn = 0; nn < 4; ++nn) {
    const int px = nn * 16 + c;
    const float gm = fmaxf(fmaxf(wred[px], wred[64 + px]),
                           fmaxf(wred[128 + px], wred[192 + px]));
    float s = 0.f;
#pragma unroll
    for (int m = 0; m < 4; ++m)
#pragma unroll
      for (int r = 0; r < 4; ++r) {
        const float e = __expf(acc[nn][m][r] - gm);
        acc[nn][m][r] = e;
        s += e;
      }
    s += __shfl_xor(s, 16, 64);
    s += __shfl_xor(s, 32, 64);
    if (g == 0) wred[256 + w * 64 + px] = s;
  }
  __syncthreads();
#pragma unroll
  for (int nn = 0; nn < 4; ++nn) {
    const int px = nn * 16 + c;
    const float s = wred[256 + px] + wred[320 + px] + wred[384 + px] + wred[448 + px];
    inv_s[nn] = 1.f / s;
  }

  // att -> bf16 into qs[px][i] (q no longer needed; all waves past barrier)
#pragma unroll
  for (int nn = 0; nn < 4; ++nn) {
    const int px = nn * 16 + c;
    const float inv = inv_s[nn];
#pragma unroll
    for (int m = 0; m < 4; ++m) {
      const int i0 = w * 64 + m * 16 + g * 4;
      uint2 pk;
      pk.x = (unsigned)f2bf(acc[nn][m][0] * inv) | ((unsigned)f2bf(acc[nn][m][1] * inv) << 16);
      pk.y = (unsigned)f2bf(acc[nn][m][2] * inv) | ((unsigned)f2bf(acc[nn][m][3] * inv) << 16);
      *(uint2*)(&qs[px * QSTR + i0]) = pk;   // 8B-aligned: i0 % 4 == 0, QSTR*2 % 8 == 0
    }
  }
  __syncthreads();

  // ---- Phase D: PV. Wave w owns px0 = 16w, d = 0..63 (4 m-frags), K=256.
  f32x4 oacc[4];
#pragma unroll
  for (int m = 0; m < 4; ++m) oacc[m] = (f32x4){0.f, 0.f, 0.f, 0.f};

  const u16* mb = memt + (size_t)n * (64 * 256);
  for (int ks = 0; ks < 8; ++ks) {
    const int k0 = ks * 32;
    const bf8 bfr = *(const bf8*)(&qs[(w * 16 + c) * QSTR + k0 + g * 8]);
#pragma unroll
    for (int m = 0; m < 4; ++m) {
      const bf8 afr = *(const bf8*)(mb + (size_t)(m * 16 + c) * 256 + k0 + g * 8);
      oacc[m] = __builtin_amdgcn_mfma_f32_16x16x32_bf16(afr, bfr, oacc[m], 0, 0, 0);
    }
  }

  float* hb = heads + ((size_t)z * HC + n * 64) * L_ + l0 + w * 16 + c;
#pragma unroll
  for (int m = 0; m < 4; ++m)
#pragma unroll
    for (int r = 0; r < 4; ++r)
      hb[(size_t)(m * 16 + g * 4 + r) * L_] = oacc[m][r];
}

// ---------------------------------------------------------------------------
// Final 1x1 conv (fp32 VALU). Unchanged.
// ---------------------------------------------------------------------------
__global__ __launch_bounds__(256) void k_out(
    const float* __restrict__ heads, const float* __restrict__ Wot,
    const float* __restrict__ bo, float* __restrict__ out, int b0) {
  __shared__ float hs[HC * 32];  // 64 KB
  const int t  = threadIdx.x;
  const int oh = blockIdx.y;
  const int z  = blockIdx.z;
  const int b  = b0 + z;
  const int l0 = blockIdx.x * 32;
  const float* hb = heads + (size_t)z * HC * L_ + l0;
#pragma unroll 8
  for (int k = 0; k < 64; ++k) {
    const int idx = t + k * 256;
    hs[idx] = hb[(idx >> 5) * L_ + (idx & 31)];
  }
  __syncthreads();

  const int o0 = oh * 128 + (t & 31) * 4;
  const int p0 = (t >> 5) * 4;

  float acc[4][4];
#pragma unroll
  for (int j = 0; j < 4; ++j)
#pragma unroll
    for (int pp = 0; pp < 4; ++pp) acc[j][pp] = 0.f;

#pragma unroll 4
  for (int m = 0; m < HC; ++m) {
    const float4 w = *(const float4*)(Wot + m * 256 + o0);
    const float4 hv = *(const float4*)(hs + m * 32 + p0);
    const float wv[4] = {w.x, w.y, w.z, w.w};
    const float ha[4] = {hv.x, hv.y, hv.z, hv.w};
#pragma unroll
    for (int j = 0; j < 4; ++j)
#pragma unroll
      for (int pp = 0; pp < 4; ++pp)
        acc[j][pp] = fmaf(wv[j], ha[pp], acc[j][pp]);
  }

#pragma unroll
  for (int j = 0; j < 4; ++j) {
    const float bias = bo[o0 + j];
    float4 r;
    r.x = acc[j][0] + bias;
    r.y = acc[j][1] + bias;
    r.z = acc[j][2] + bias;
    r.w = acc[j][3] + bias;
    *(float4*)(out + ((size_t)b * OD + o0 + j) * L_ + l0 + p0) = r;
  }
}

// ---------------------------------------------------------------------------
extern "C" void kernel_launch(void* const* d_in, const int* in_sizes, int n_in,
                              void* d_out, int out_size, void* d_ws, size_t ws_size,
                              hipStream_t stream) {
  const float* x    = (const float*)d_in[0];
  const float* Wp   = (const float*)d_in[1];
  const float* bp   = (const float*)d_in[2];
  const float* keyb = (const float*)d_in[3];
  const float* memb = (const float*)d_in[4];
  const float* Wo   = (const float*)d_in[5];
  const float* bo   = (const float*)d_in[6];
  float* out = (float*)d_out;

  // ws layout: Wpt | Wot | Ktb | memt | heads
  const size_t WPT_B = (size_t)C_ * 256 * 4;        // 262144
  const size_t WOT_B = (size_t)HC * 256 * 4;        // 524288
  const size_t KTB_B = (size_t)NH * 256 * 288 * 2;  // 1179648
  const size_t MEM_B = (size_t)NH * 64 * 256 * 2;   // 262144
  const size_t HB1_B = (size_t)HC * L_ * 4;         // 8 MB per batch
  char* ws = (char*)d_ws;
  float* Wpt   = (float*)ws;
  float* Wot   = (float*)(ws + WPT_B);
  u16*   Ktb   = (u16*)  (ws + WPT_B + WOT_B);
  u16*   memt  = (u16*)  (ws + WPT_B + WOT_B + KTB_B);
  float* heads = (float*)(ws + WPT_B + WOT_B + KTB_B + MEM_B);

  float* proj = out;  // proj scratch in d_out; consumed before k_out overwrites

  hipLaunchKernelGGL(k_transpose, dim3(512),  dim3(256), 0, stream, Wp, Wo, Wpt, Wot);
  hipLaunchKernelGGL(k_prep,      dim3(4352), dim3(256), 0, stream, keyb, memb, Ktb, memt);
  hipLaunchKernelGGL(k_proj,      dim3(64, 8), dim3(256), 0, stream, x, Wpt, bp, proj);

  if (ws_size >= WPT_B + WOT_B + KTB_B + MEM_B + 8 * HB1_B) {
    hipLaunchKernelGGL(k_attn_mfma, dim3(64, 8, 8), dim3(256), 0, stream,
                       proj, Ktb, memt, heads, 0);
    hipLaunchKernelGGL(k_out,       dim3(128, 2, 8), dim3(256), 0, stream,
                       heads, Wot, bo, out, 0);
  } else {
    for (int b = 0; b < 8; ++b) {
      hipLaunchKernelGGL(k_attn_mfma, dim3(64, 8, 1), dim3(256), 0, stream,
                         proj, Ktb, memt, heads, b);
      hipLaunchKernelGGL(k_out,       dim3(128, 2, 1), dim3(256), 0, stream,
                         heads, Wot, bo, out, b);
    }
  }
}

// Round 6
// 476.173 us; speedup vs baseline: 2.4203x; 1.1376x over previous
//
#include <hip/hip_runtime.h>
#include <cstdint>
#include <cstddef>

// Problem constants
#define L_  4096   // H*W
#define C_  256    // IN_DIM
#define NH  8
#define KK  288    // 32*9
#define MM  256    // MEM_DIM
#define DD  64
#define HC  512
#define OD  256

typedef unsigned short u16;
typedef __attribute__((ext_vector_type(8))) short bf8;    // 8 bf16
typedef __attribute__((ext_vector_type(4))) float f32x4;

static __device__ __forceinline__ u16 f2bf(float f) {
  union { float f; unsigned u; } v; v.f = f;
  const unsigned r = v.u + 0x7FFFu + ((v.u >> 16) & 1u);
  return (u16)(r >> 16);
}
static __device__ __forceinline__ unsigned pk2(float a, float b) {
  return (unsigned)f2bf(a) | ((unsigned)f2bf(b) << 16);
}

// ---------------------------------------------------------------------------
// Wpt[c][o] = W_proj[o][c]  (for fp32 k_proj)
// ---------------------------------------------------------------------------
__global__ __launch_bounds__(256) void k_transpose(
    const float* __restrict__ Wp, float* __restrict__ Wpt) {
  Wpt[threadIdx.x * 256 + blockIdx.x] = Wp[blockIdx.x * 256 + threadIdx.x];
}

// ---------------------------------------------------------------------------
// Prep bf16 operand banks:
//  Ktb [n][i=256][a=288]  <- key_bank [n][a][i]
//  memt[n][d=64][i=256]   <- memory_bank [n][i][d]
//  Wob [o=256][m=512]     <- W_out (no transpose, just bf16)
// ---------------------------------------------------------------------------
__global__ __launch_bounds__(256) void k_prep(
    const float* __restrict__ keyb, const float* __restrict__ memb,
    const float* __restrict__ Wo, u16* __restrict__ Ktb,
    u16* __restrict__ memt, u16* __restrict__ Wob) {
  const int t = threadIdx.x;
  const int bid = blockIdx.x;
  if (bid < 2304) {
    const int nh = bid / 288, a = bid - nh * 288;
    Ktb[(size_t)nh * (256 * 288) + (size_t)t * 288 + a] =
        f2bf(keyb[((size_t)nh * 288 + a) * 256 + t]);
  } else if (bid < 4352) {
    const int q = bid - 2304;
    const int nh = q >> 8, i = q & 255;
    if (t < 64)
      memt[(size_t)nh * (64 * 256) + (size_t)t * 256 + i] =
          f2bf(memb[((size_t)nh * 256 + i) * 64 + t]);
  } else {
    const int q = bid - 4352;             // 0..511
    const int o = q >> 1, half = q & 1;
    Wob[(size_t)o * 512 + half * 256 + t] = f2bf(Wo[(size_t)o * 512 + half * 256 + t]);
  }
}

// ---------------------------------------------------------------------------
// 1x1 conv projection (fp32 VALU), output stored as bf16 [b][c][l] in d_out.
// ---------------------------------------------------------------------------
__global__ __launch_bounds__(256) void k_proj(
    const float* __restrict__ x, const float* __restrict__ Wpt,
    const float* __restrict__ bp, u16* __restrict__ projb) {
  __shared__ float xs[C_ * 64];  // 64 KB
  const int t  = threadIdx.x;
  const int b  = blockIdx.y;
  const int l0 = blockIdx.x * 64;
  const float* xb = x + (size_t)b * C_ * L_ + l0;
#pragma unroll 8
  for (int k = 0; k < 64; ++k) {
    const int idx = t + k * 256;
    xs[idx] = xb[(idx >> 6) * L_ + (idx & 63)];
  }
  __syncthreads();

  const int o0 = (t & 63) * 4;
  const int p0 = (t >> 6) * 16;

  float acc[4][16];
#pragma unroll
  for (int j = 0; j < 4; ++j)
#pragma unroll
    for (int i = 0; i < 16; ++i) acc[j][i] = 0.f;

  for (int c = 0; c < C_; ++c) {
    const float4 w = *(const float4*)(Wpt + c * 256 + o0);
    const float* xr = xs + c * 64 + p0;
    float xv[16];
#pragma unroll
    for (int i = 0; i < 16; i += 4) {
      const float4 xq = *(const float4*)(xr + i);
      xv[i] = xq.x; xv[i + 1] = xq.y; xv[i + 2] = xq.z; xv[i + 3] = xq.w;
    }
#pragma unroll
    for (int i = 0; i < 16; ++i) {
      acc[0][i] = fmaf(w.x, xv[i], acc[0][i]);
      acc[1][i] = fmaf(w.y, xv[i], acc[1][i]);
      acc[2][i] = fmaf(w.z, xv[i], acc[2][i]);
      acc[3][i] = fmaf(w.w, xv[i], acc[3][i]);
    }
  }

#pragma unroll
  for (int j = 0; j < 4; ++j) {
    const float bias = bp[o0 + j];
    u16* pr = projb + ((size_t)b * C_ + o0 + j) * L_ + l0 + p0;
    uint4 A, B;
    A.x = pk2(acc[j][0] + bias,  acc[j][1] + bias);
    A.y = pk2(acc[j][2] + bias,  acc[j][3] + bias);
    A.z = pk2(acc[j][4] + bias,  acc[j][5] + bias);
    A.w = pk2(acc[j][6] + bias,  acc[j][7] + bias);
    B.x = pk2(acc[j][8] + bias,  acc[j][9] + bias);
    B.y = pk2(acc[j][10] + bias, acc[j][11] + bias);
    B.z = pk2(acc[j][12] + bias, acc[j][13] + bias);
    B.w = pk2(acc[j][14] + bias, acc[j][15] + bias);
    *(uint4*)(pr)     = A;
    *(uint4*)(pr + 8) = B;
  }
}

// ---------------------------------------------------------------------------
// Unfold: projb (bf16, one batch) -> Qt[n][y*64+px][a] bf16, 16B chunks
// pre-swizzled in global: chunk j (j<32) stored at position j ^ (px&7).
// LDS swizzle is R-FORM everywhere: within-row chunk index XORed with
// (px>>3)&7, then added to the row base (round-5 bug: XOR on the absolute
// byte address disagrees with the R-form reader when px odd & s>=4,
// leaving some slots unwritten -> NaN).
// ---------------------------------------------------------------------------
__global__ __launch_bounds__(256) void k_unfold(
    const u16* __restrict__ projb, u16* __restrict__ Qt) {
  __shared__ __align__(16) u16 qs[64 * 288];   // 36,864 B
  __shared__ int toff[KK];                      // c*4096
  __shared__ int tpk[KK];                       // (dy+1)*4 + (dx+1)
  const int t = threadIdx.x;
  const int y = blockIdx.x;
  const int n = blockIdx.y;

  for (int tt = t; tt < KK; tt += 256) {
    const unsigned g = (unsigned)tt * 8u + (unsigned)n;
    const unsigned c = g / 9u;
    const unsigned p = g - c * 9u;
    const int dy = (int)(p / 3u) - 1;
    const int dx = (int)(p % 3u) - 1;
    toff[tt] = (int)(c << 12);
    tpk[tt]  = (dy + 1) * 4 + (dx + 1);
  }
  __syncthreads();

  // gather: 8 lanes per a, each loads an aligned 8-px bf16 chunk, scatters
  for (int i = 0; i < 9; ++i) {
    const int e  = t + i * 256;        // 0..2303
    const int a  = e >> 3;
    const int xc = (e & 7) * 8;
    const int pk = tpk[a];
    const int dx = (pk & 3) - 1;
    const int yy = y + (pk >> 2) - 1;
    u16 vals[8];
    if ((unsigned)yy < 64u) {
      const bf8 vv = *(const bf8*)(projb + toff[a] + yy * 64 + xc);
#pragma unroll
      for (int k2 = 0; k2 < 8; ++k2) vals[k2] = (u16)(((const short*)&vv)[k2]);
    } else {
#pragma unroll
      for (int k2 = 0; k2 < 8; ++k2) vals[k2] = 0;
    }
#pragma unroll
    for (int k2 = 0; k2 < 8; ++k2) {
      const int px = xc + k2 - dx;
      if ((unsigned)px < 64u) {
        int byte_off;
        if (a < 256) {
          const int s = (px >> 3) & 7;
          byte_off = px * 576 + ((((a >> 3) ^ s)) << 4) + ((a & 7) * 2);  // R-form
        } else {
          byte_off = px * 576 + a * 2;
        }
        *(u16*)((char*)qs + byte_off) = vals[k2];
      }
    }
  }
  // zero the never-written edge column for dx = +/-1 rows
  for (int tt = t; tt < KK; tt += 256) {
    const int dx = (tpk[tt] & 3) - 1;
    if (dx != 0) {
      const int px = (dx == 1) ? 63 : 0;
      int byte_off;
      if (tt < 256) {
        const int s = (px >> 3) & 7;
        byte_off = px * 576 + ((((tt >> 3) ^ s)) << 4) + ((tt & 7) * 2);  // R-form
      } else {
        byte_off = px * 576 + tt * 2;
      }
      *(u16*)((char*)qs + byte_off) = 0;
    }
  }
  __syncthreads();

  // write out: 16B chunks, global position swizzled with px&7 (j<32)
  u16* qrow = Qt + (size_t)n * (L_ * 288) + (size_t)y * (64 * 288);
  for (int i = 0; i < 9; ++i) {
    const int ci = t + i * 256;        // 0..2303
    const int px = ci / 36;
    const int j  = ci - px * 36;
    int rb = px * 576 + j * 16;
    if (j < 32) rb = px * 576 + ((j ^ ((px >> 3) & 7)) * 16);
    const bf8 v = *(const bf8*)((char*)qs + rb);
    const int js = (j < 32) ? (j ^ (px & 7)) : j;
    *(bf8*)(qrow + px * 288 + js * 8) = v;
  }
}

// ---------------------------------------------------------------------------
// MFMA attention per (y-row, head) for one batch.
// ---------------------------------------------------------------------------
__global__ __launch_bounds__(256) void k_attn2(
    const u16* __restrict__ Qt, const u16* __restrict__ Ktb,
    const u16* __restrict__ memt, u16* __restrict__ heads2) {
  __shared__ __align__(16) u16 qs[64 * 288];   // 36,864 B; att + transpose alias
  __shared__ float wred[512];
  const int t    = threadIdx.x;
  const int w    = t >> 6;
  const int lane = t & 63;
  const int c    = lane & 15;
  const int g    = lane >> 4;
  const int y    = blockIdx.x;
  const int n    = blockIdx.y;

  // stage: linear 16B copy (Qt chunks pre-swizzled)
  const u16* src = Qt + (size_t)n * (L_ * 288) + (size_t)y * (64 * 288);
  for (int i = 0; i < 9; ++i) {
    const int ci = i * 256 + t;
    *(bf8*)(qs + ci * 8) = *(const bf8*)(src + ci * 8);
  }
  __syncthreads();

  // ---- logits
  f32x4 acc[4][4];
#pragma unroll
  for (int nn = 0; nn < 4; ++nn)
#pragma unroll
    for (int m = 0; m < 4; ++m) acc[nn][m] = (f32x4){0.f, 0.f, 0.f, 0.f};

  const u16* kb = Ktb + (size_t)n * (256 * 288);
  for (int ks = 0; ks < 9; ++ks) {
    const int k0 = ks * 32;
    const int j  = ks * 4 + g;
    bf8 bfr[4];
#pragma unroll
    for (int nn = 0; nn < 4; ++nn) {
      const int px = nn * 16 + c;
      const int jj = (j < 32) ? (j ^ (px & 7)) : j;
      bfr[nn] = *(const bf8*)(qs + px * 288 + jj * 8);
    }
#pragma unroll
    for (int m = 0; m < 4; ++m) {
      const bf8 afr = *(const bf8*)(kb + (size_t)(w * 64 + m * 16 + c) * 288 + k0 + g * 8);
#pragma unroll
      for (int nn = 0; nn < 4; ++nn)
        acc[nn][m] = __builtin_amdgcn_mfma_f32_16x16x32_bf16(afr, bfr[nn], acc[nn][m], 0, 0, 0);
    }
  }

  // ---- softmax over i (i = w*64 + m*16 + g*4 + r, px = nn*16 + c)
#pragma unroll
  for (int nn = 0; nn < 4; ++nn) {
    float m0 = acc[nn][0][0];
#pragma unroll
    for (int m = 0; m < 4; ++m)
#pragma unroll
      for (int r = 0; r < 4; ++r) m0 = fmaxf(m0, acc[nn][m][r]);
    m0 = fmaxf(m0, __shfl_xor(m0, 16, 64));
    m0 = fmaxf(m0, __shfl_xor(m0, 32, 64));
    if (g == 0) wred[w * 64 + nn * 16 + c] = m0;
  }
  __syncthreads();
  float inv_s[4];
#pragma unroll
  for (int nn = 0; nn < 4; ++nn) {
    const int px = nn * 16 + c;
    const float gm = fmaxf(fmaxf(wred[px], wred[64 + px]),
                           fmaxf(wred[128 + px], wred[192 + px]));
    float s = 0.f;
#pragma unroll
    for (int m = 0; m < 4; ++m)
#pragma unroll
      for (int r = 0; r < 4; ++r) {
        const float e = __expf(acc[nn][m][r] - gm);
        acc[nn][m][r] = e;
        s += e;
      }
    s += __shfl_xor(s, 16, 64);
    s += __shfl_xor(s, 32, 64);
    if (g == 0) wred[256 + w * 64 + px] = s;
  }
  __syncthreads();
#pragma unroll
  for (int nn = 0; nn < 4; ++nn) {
    const int px = nn * 16 + c;
    inv_s[nn] = 1.f / (wred[256 + px] + wred[320 + px] + wred[384 + px] + wred[448 + px]);
  }

  // att -> bf16 into qs, layout elem = px*256 + ((i/8)^(px&7))*8 + (i&7)
#pragma unroll
  for (int nn = 0; nn < 4; ++nn) {
    const int px = nn * 16 + c;
    const float inv = inv_s[nn];
#pragma unroll
    for (int m = 0; m < 4; ++m) {
      const int i0 = w * 64 + m * 16 + g * 4;
      uint2 pkv;
      pkv.x = pk2(acc[nn][m][0] * inv, acc[nn][m][1] * inv);
      pkv.y = pk2(acc[nn][m][2] * inv, acc[nn][m][3] * inv);
      const int chunk = (i0 >> 3) ^ (px & 7);
      *(uint2*)(qs + px * 256 + chunk * 8 + (g & 1) * 4) = pkv;
    }
  }
  __syncthreads();

  // ---- PV: wave w owns px = w*16 + c, d = 0..63
  f32x4 oacc[4];
#pragma unroll
  for (int m = 0; m < 4; ++m) oacc[m] = (f32x4){0.f, 0.f, 0.f, 0.f};
  const u16* mb = memt + (size_t)n * (64 * 256);
  const int pxd = w * 16 + c;
  for (int ks = 0; ks < 8; ++ks) {
    const int k0 = ks * 32;
    const int j  = ks * 4 + g;
    const bf8 bfr = *(const bf8*)(qs + pxd * 256 + ((j ^ (pxd & 7)) * 8));
#pragma unroll
    for (int m = 0; m < 4; ++m) {
      const bf8 afr = *(const bf8*)(mb + (size_t)(m * 16 + c) * 256 + k0 + g * 8);
      oacc[m] = __builtin_amdgcn_mfma_f32_16x16x32_bf16(afr, bfr, oacc[m], 0, 0, 0);
    }
  }

  // ---- epilogue: transpose via LDS (stride 68 f32), emit heads2[px][m] bf16
  __syncthreads();
  float* trf = (float*)qs;   // 64 x 68 f32 = 17,408 B
#pragma unroll
  for (int m = 0; m < 4; ++m) {
    float* tp = trf + pxd * 68 + m * 16 + g * 4;
    *(float2*)(tp)     = make_float2(oacc[m][0], oacc[m][1]);
    *(float2*)(tp + 2) = make_float2(oacc[m][2], oacc[m][3]);
  }
  __syncthreads();
  {
    const int px2 = t >> 2, q = t & 3;
    const float* tr = trf + px2 * 68 + q * 16;
    const float4 v0 = *(const float4*)(tr);
    const float4 v1 = *(const float4*)(tr + 4);
    const float4 v2 = *(const float4*)(tr + 8);
    const float4 v3 = *(const float4*)(tr + 12);
    uint4 A, B;
    A.x = pk2(v0.x, v0.y); A.y = pk2(v0.z, v0.w);
    A.z = pk2(v1.x, v1.y); A.w = pk2(v1.z, v1.w);
    B.x = pk2(v2.x, v2.y); B.y = pk2(v2.z, v2.w);
    B.z = pk2(v3.x, v3.y); B.w = pk2(v3.z, v3.w);
    u16* hb = heads2 + ((size_t)y * 64 + px2) * HC + n * 64 + q * 16;
    *(uint4*)(hb)     = A;
    *(uint4*)(hb + 8) = B;
  }
}

// ---------------------------------------------------------------------------
// Final 1x1 conv via MFMA: out[b][o][l] = Wob[o][m] * heads2[b][l][m] + bo[o]
// ---------------------------------------------------------------------------
__global__ __launch_bounds__(256) void k_out_mfma(
    const u16* __restrict__ heads2, const u16* __restrict__ Wob,
    const float* __restrict__ bo, float* __restrict__ out) {
  const int t    = threadIdx.x;
  const int w    = t >> 6;
  const int lane = t & 63;
  const int c    = lane & 15;
  const int g    = lane >> 4;
  const int y    = blockIdx.x;
  const int b    = blockIdx.y;
  const u16* hb = heads2 + ((size_t)b * L_ + (size_t)y * 64) * HC;

  f32x4 acc[4][4];
#pragma unroll
  for (int nn = 0; nn < 4; ++nn)
#pragma unroll
    for (int m = 0; m < 4; ++m) acc[nn][m] = (f32x4){0.f, 0.f, 0.f, 0.f};

  for (int ks = 0; ks < 16; ++ks) {
    const int k0 = ks * 32;
    bf8 bfr[4];
#pragma unroll
    for (int nn = 0; nn < 4; ++nn)
      bfr[nn] = *(const bf8*)(hb + (size_t)(nn * 16 + c) * HC + k0 + g * 8);
#pragma unroll
    for (int m = 0; m < 4; ++m) {
      const bf8 afr = *(const bf8*)(Wob + (size_t)(w * 64 + m * 16 + c) * HC + k0 + g * 8);
#pragma unroll
      for (int nn = 0; nn < 4; ++nn)
        acc[nn][m] = __builtin_amdgcn_mfma_f32_16x16x32_bf16(afr, bfr[nn], acc[nn][m], 0, 0, 0);
    }
  }

  float* ob = out + (size_t)b * OD * L_ + (size_t)y * 64;
#pragma unroll
  for (int m = 0; m < 4; ++m)
#pragma unroll
    for (int r = 0; r < 4; ++r) {
      const int o = w * 64 + m * 16 + g * 4 + r;
      const float bias = bo[o];
#pragma unroll
      for (int nn = 0; nn < 4; ++nn)
        ob[(size_t)o * L_ + nn * 16 + c] = acc[nn][m][r] + bias;
    }
}

// ---------------------------------------------------------------------------
extern "C" void kernel_launch(void* const* d_in, const int* in_sizes, int n_in,
                              void* d_out, int out_size, void* d_ws, size_t ws_size,
                              hipStream_t stream) {
  const float* x    = (const float*)d_in[0];
  const float* Wp   = (const float*)d_in[1];
  const float* bp   = (const float*)d_in[2];
  const float* keyb = (const float*)d_in[3];
  const float* memb = (const float*)d_in[4];
  const float* Wo   = (const float*)d_in[5];
  const float* bo   = (const float*)d_in[6];
  float* out = (float*)d_out;

  // ws layout: Wpt | Ktb | memt | Wob | Qt(1 batch) | heads2(all batches)
  // total = 54.4 MB; ws_size >= 66.1 MB established (round-2/3 full-batch path ran).
  const size_t WPT_B = (size_t)C_ * 256 * 4;         //   262,144
  const size_t KTB_B = (size_t)NH * 256 * 288 * 2;   // 1,179,648
  const size_t MEM_B = (size_t)NH * 64 * 256 * 2;    //   262,144
  const size_t WOB_B = (size_t)OD * HC * 2;          //   262,144
  const size_t QT_B  = (size_t)NH * L_ * 288 * 2;    // 18,874,368
  char* ws = (char*)d_ws;
  float* Wpt    = (float*)ws;
  u16*   Ktb    = (u16*)(ws + WPT_B);
  u16*   memt   = (u16*)(ws + WPT_B + KTB_B);
  u16*   Wob    = (u16*)(ws + WPT_B + KTB_B + MEM_B);
  u16*   Qt     = (u16*)(ws + WPT_B + KTB_B + MEM_B + WOB_B);
  u16*   heads2 = (u16*)(ws + WPT_B + KTB_B + MEM_B + WOB_B + QT_B);

  u16* projb = (u16*)d_out;  // bf16 proj [b][c][l] = 16.8 MB; consumed before k_out

  hipLaunchKernelGGL(k_transpose, dim3(256),   dim3(256), 0, stream, Wp, Wpt);
  hipLaunchKernelGGL(k_prep,      dim3(4864),  dim3(256), 0, stream, keyb, memb, Wo, Ktb, memt, Wob);
  hipLaunchKernelGGL(k_proj,      dim3(64, 8), dim3(256), 0, stream, x, Wpt, bp, projb);

  for (int b = 0; b < 8; ++b) {
    hipLaunchKernelGGL(k_unfold, dim3(64, 8), dim3(256), 0, stream,
                       projb + (size_t)b * C_ * L_, Qt);
    hipLaunchKernelGGL(k_attn2,  dim3(64, 8), dim3(256), 0, stream,
                       Qt, Ktb, memt, heads2 + (size_t)b * L_ * HC);
  }
  hipLaunchKernelGGL(k_out_mfma, dim3(64, 8), dim3(256), 0, stream,
                     heads2, Wob, bo, out);
}

// Round 7
// 321.062 us; speedup vs baseline: 3.5897x; 1.4831x over previous
//
#include <hip/hip_runtime.h>
#include <cstdint>
#include <cstddef>

// Problem constants
#define L_  4096   // H*W
#define C_  256    // IN_DIM
#define NH  8
#define KK  288    // 32*9
#define MM  256    // MEM_DIM
#define DD  64
#define HC  512
#define OD  256

typedef unsigned short u16;
typedef __attribute__((ext_vector_type(8))) short bf8;    // 8 bf16
typedef __attribute__((ext_vector_type(4))) float f32x4;

static __device__ __forceinline__ u16 f2bf(float f) {
  union { float f; unsigned u; } v; v.f = f;
  const unsigned r = v.u + 0x7FFFu + ((v.u >> 16) & 1u);
  return (u16)(r >> 16);
}
static __device__ __forceinline__ unsigned pk2(float a, float b) {
  return (unsigned)f2bf(a) | ((unsigned)f2bf(b) << 16);
}

// ---------------------------------------------------------------------------
// Prep bf16 operand banks:
//  Ktb [n][i=256][a=288] <- key_bank[n][a][i]
//  memt[n][d=64][i=256]  <- memory_bank[n][i][d]
//  Wob [o=256][m=512]    <- W_out  (bf16, no transpose)
//  Wpb [o=256][c=256]    <- W_proj (bf16, no transpose)
// grid: 2304 + 2048 + 512 + 256 = 5120 blocks
// ---------------------------------------------------------------------------
__global__ __launch_bounds__(256) void k_prep(
    const float* __restrict__ keyb, const float* __restrict__ memb,
    const float* __restrict__ Wo, const float* __restrict__ Wp,
    u16* __restrict__ Ktb, u16* __restrict__ memt,
    u16* __restrict__ Wob, u16* __restrict__ Wpb) {
  const int t = threadIdx.x;
  const int bid = blockIdx.x;
  if (bid < 2304) {
    const int nh = bid / 288, a = bid - nh * 288;
    Ktb[(size_t)nh * (256 * 288) + (size_t)t * 288 + a] =
        f2bf(keyb[((size_t)nh * 288 + a) * 256 + t]);
  } else if (bid < 4352) {
    const int q = bid - 2304;
    const int nh = q >> 8, i = q & 255;
    if (t < 64)
      memt[(size_t)nh * (64 * 256) + (size_t)t * 256 + i] =
          f2bf(memb[((size_t)nh * 256 + i) * 64 + t]);
  } else if (bid < 4864) {
    const int q = bid - 4352;             // 0..511
    const int o = q >> 1, half = q & 1;
    Wob[(size_t)o * 512 + half * 256 + t] = f2bf(Wo[(size_t)o * 512 + half * 256 + t]);
  } else {
    const int o = bid - 4864;             // 0..255
    Wpb[(size_t)o * 256 + t] = f2bf(Wp[(size_t)o * 256 + t]);
  }
}

// ---------------------------------------------------------------------------
// 1x1 conv projection via MFMA: proj[b][o][l] = W_proj x + b, bf16 out.
// Per block (y-row, b): 256o x 64px, K=256.
// LDS xs: bf16 [c=256][px=64], px XOR-swizzled with (c>>3)&7 so that
//  - staged uint2 stores (4 px / 1 c) are conflict-free (lane spread over px)
//  - frag reads (8 k / fixed px) are conflict-free (k>>3 varies per g-group)
// ---------------------------------------------------------------------------
__global__ __launch_bounds__(256) void k_proj_mfma(
    const float* __restrict__ x, const u16* __restrict__ Wpb,
    const float* __restrict__ bp, u16* __restrict__ projb) {
  __shared__ __align__(16) u16 xs[C_ * 64];  // 32 KB
  const int t    = threadIdx.x;
  const int w    = t >> 6;
  const int lane = t & 63;
  const int c    = lane & 15;
  const int g    = lane >> 4;
  const int y    = blockIdx.x;
  const int b    = blockIdx.y;
  const int l0   = y * 64;
  const float* xb = x + (size_t)b * C_ * L_ + l0;

  // stage: coalesced float4 loads along l, bf16 pack, swizzled store
  for (int i = 0; i < 16; ++i) {
    const int idx = t + i * 256;        // 0..4095
    const int cc  = idx >> 4;           // 0..255
    const int p4  = (idx & 15) * 4;     // 0..60 step 4
    const float4 v = *(const float4*)(xb + (size_t)cc * L_ + p4);
    const int ps = p4 ^ (((cc >> 3) & 7) << 3);
    uint2 pkv;
    pkv.x = pk2(v.x, v.y);
    pkv.y = pk2(v.z, v.w);
    *(uint2*)(xs + cc * 64 + ps) = pkv;
  }
  __syncthreads();

  f32x4 acc[4][4];
#pragma unroll
  for (int nn = 0; nn < 4; ++nn)
#pragma unroll
    for (int m = 0; m < 4; ++m) acc[nn][m] = (f32x4){0.f, 0.f, 0.f, 0.f};

  for (int ks = 0; ks < 8; ++ks) {
    const int k0 = ks * 32;
    bf8 bfr[4];
#pragma unroll
    for (int nn = 0; nn < 4; ++nn) {
      const int px = nn * 16 + c;
      bf8 fr;
#pragma unroll
      for (int j = 0; j < 8; ++j) {
        const int k = k0 + g * 8 + j;
        fr[j] = (short)xs[k * 64 + (px ^ (((k >> 3) & 7) << 3))];
      }
      bfr[nn] = fr;
    }
#pragma unroll
    for (int m = 0; m < 4; ++m) {
      const bf8 afr = *(const bf8*)(Wpb + (size_t)(w * 64 + m * 16 + c) * 256 + k0 + g * 8);
#pragma unroll
      for (int nn = 0; nn < 4; ++nn)
        acc[nn][m] = __builtin_amdgcn_mfma_f32_16x16x32_bf16(afr, bfr[nn], acc[nn][m], 0, 0, 0);
    }
  }

  u16* pb = projb + (size_t)b * C_ * L_ + l0;
#pragma unroll
  for (int m = 0; m < 4; ++m)
#pragma unroll
    for (int r = 0; r < 4; ++r) {
      const int o = w * 64 + m * 16 + g * 4 + r;
      const float bias = bp[o];
#pragma unroll
      for (int nn = 0; nn < 4; ++nn)
        pb[(size_t)o * L_ + nn * 16 + c] = f2bf(acc[nn][m][r] + bias);
    }
}

// ---------------------------------------------------------------------------
// Fused unfold + MFMA attention per (y-row, head, batch). ONE launch, 4096 blk.
//  Phase A: table-free unfold gather projb -> qs[px][a] bf16,
//           chunk-swizzled: chunk (a>>3, a<256) stored at (a>>3)^(px&7).
//  Phase B: logits = Ktb (A, 256x288) x qs (B, 288x64)
//  Phase C: wave-parallel softmax over i, 4-wave LDS combine
//  Phase D: att bf16 -> qs (512B rows, chunk^(px&7)); PV = memt x att
//  Phase E: LDS transpose -> heads2[b][px][n*64+d] bf16 coalesced
// ---------------------------------------------------------------------------
__global__ __launch_bounds__(256) void k_fat(
    const u16* __restrict__ projb, const u16* __restrict__ Ktb,
    const u16* __restrict__ memt, u16* __restrict__ heads2) {
  __shared__ __align__(16) u16 qs[64 * 288];   // 36,864 B; att + transpose alias
  __shared__ float wred[512];
  const int t    = threadIdx.x;
  const int w    = t >> 6;
  const int lane = t & 63;
  const int c    = lane & 15;
  const int g    = lane >> 4;
  const int y    = blockIdx.x;
  const int n    = blockIdx.y;
  const int bb   = blockIdx.z;
  const u16* pb = projb + (size_t)bb * C_ * L_;

  // ---- Phase A: unfold gather (8 lanes per a, aligned 8-px chunks, scatter)
  for (int i = 0; i < 9; ++i) {
    const int e  = t + i * 256;        // 0..2303
    const int a  = e >> 3;
    const int xc = (e & 7) * 8;
    const unsigned gg = (unsigned)a * 8u + (unsigned)n;
    const unsigned cc = gg / 9u;
    const unsigned p  = gg - cc * 9u;
    const int dy = (int)(p / 3u) - 1;
    const int dx = (int)(p % 3u) - 1;
    const int yy = y + dy;
    u16 vals[8];
    if ((unsigned)yy < 64u) {
      const bf8 vv = *(const bf8*)(pb + ((size_t)cc << 12) + yy * 64 + xc);
#pragma unroll
      for (int k2 = 0; k2 < 8; ++k2) vals[k2] = (u16)(((const short*)&vv)[k2]);
    } else {
#pragma unroll
      for (int k2 = 0; k2 < 8; ++k2) vals[k2] = 0;
    }
#pragma unroll
    for (int k2 = 0; k2 < 8; ++k2) {
      const int px = xc + k2 - dx;
      if ((unsigned)px < 64u) {
        int off;
        if (a < 256) off = px * 576 + ((((a >> 3) ^ (px & 7))) << 4) + ((a & 7) * 2);
        else         off = px * 576 + a * 2;
        *(u16*)((char*)qs + off) = vals[k2];
      }
    }
  }
  // zero the never-written edge column for dx = +/-1 rows
  for (int tt = t; tt < KK; tt += 256) {
    const unsigned gg = (unsigned)tt * 8u + (unsigned)n;
    const unsigned cc = gg / 9u;
    const unsigned p  = gg - cc * 9u;
    const int dx = (int)(p % 3u) - 1;
    if (dx != 0) {
      const int px = (dx == 1) ? 63 : 0;
      int off;
      if (tt < 256) off = px * 576 + ((((tt >> 3) ^ (px & 7))) << 4) + ((tt & 7) * 2);
      else          off = px * 576 + tt * 2;
      *(u16*)((char*)qs + off) = 0;
    }
  }
  __syncthreads();

  // ---- Phase B: logits
  f32x4 acc[4][4];
#pragma unroll
  for (int nn = 0; nn < 4; ++nn)
#pragma unroll
    for (int m = 0; m < 4; ++m) acc[nn][m] = (f32x4){0.f, 0.f, 0.f, 0.f};

  const u16* kb = Ktb + (size_t)n * (256 * 288);
  for (int ks = 0; ks < 9; ++ks) {
    const int k0 = ks * 32;
    const int j  = ks * 4 + g;
    bf8 bfr[4];
#pragma unroll
    for (int nn = 0; nn < 4; ++nn) {
      const int px = nn * 16 + c;
      const int jj = (j < 32) ? (j ^ (px & 7)) : j;
      bfr[nn] = *(const bf8*)(qs + px * 288 + jj * 8);
    }
#pragma unroll
    for (int m = 0; m < 4; ++m) {
      const bf8 afr = *(const bf8*)(kb + (size_t)(w * 64 + m * 16 + c) * 288 + k0 + g * 8);
#pragma unroll
      for (int nn = 0; nn < 4; ++nn)
        acc[nn][m] = __builtin_amdgcn_mfma_f32_16x16x32_bf16(afr, bfr[nn], acc[nn][m], 0, 0, 0);
    }
  }

  // ---- Phase C: softmax over i (i = w*64 + m*16 + g*4 + r, px = nn*16 + c)
#pragma unroll
  for (int nn = 0; nn < 4; ++nn) {
    float m0 = acc[nn][0][0];
#pragma unroll
    for (int m = 0; m < 4; ++m)
#pragma unroll
      for (int r = 0; r < 4; ++r) m0 = fmaxf(m0, acc[nn][m][r]);
    m0 = fmaxf(m0, __shfl_xor(m0, 16, 64));
    m0 = fmaxf(m0, __shfl_xor(m0, 32, 64));
    if (g == 0) wred[w * 64 + nn * 16 + c] = m0;
  }
  __syncthreads();
  float inv_s[4];
#pragma unroll
  for (int nn = 0; nn < 4; ++nn) {
    const int px = nn * 16 + c;
    const float gm = fmaxf(fmaxf(wred[px], wred[64 + px]),
                           fmaxf(wred[128 + px], wred[192 + px]));
    float s = 0.f;
#pragma unroll
    for (int m = 0; m < 4; ++m)
#pragma unroll
      for (int r = 0; r < 4; ++r) {
        const float e = __expf(acc[nn][m][r] - gm);
        acc[nn][m][r] = e;
        s += e;
      }
    s += __shfl_xor(s, 16, 64);
    s += __shfl_xor(s, 32, 64);
    if (g == 0) wred[256 + w * 64 + px] = s;
  }
  __syncthreads();
#pragma unroll
  for (int nn = 0; nn < 4; ++nn) {
    const int px = nn * 16 + c;
    inv_s[nn] = 1.f / (wred[256 + px] + wred[320 + px] + wred[384 + px] + wred[448 + px]);
  }

  // att -> bf16 into qs, layout elem = px*256 + ((i/8)^(px&7))*8 + (i&7)
#pragma unroll
  for (int nn = 0; nn < 4; ++nn) {
    const int px = nn * 16 + c;
    const float inv = inv_s[nn];
#pragma unroll
    for (int m = 0; m < 4; ++m) {
      const int i0 = w * 64 + m * 16 + g * 4;
      uint2 pkv;
      pkv.x = pk2(acc[nn][m][0] * inv, acc[nn][m][1] * inv);
      pkv.y = pk2(acc[nn][m][2] * inv, acc[nn][m][3] * inv);
      const int chunk = (i0 >> 3) ^ (px & 7);
      *(uint2*)(qs + px * 256 + chunk * 8 + (g & 1) * 4) = pkv;
    }
  }
  __syncthreads();

  // ---- Phase D: PV. Wave w owns px = w*16 + c, d = 0..63
  f32x4 oacc[4];
#pragma unroll
  for (int m = 0; m < 4; ++m) oacc[m] = (f32x4){0.f, 0.f, 0.f, 0.f};
  const u16* mb = memt + (size_t)n * (64 * 256);
  const int pxd = w * 16 + c;
  for (int ks = 0; ks < 8; ++ks) {
    const int k0 = ks * 32;
    const int j  = ks * 4 + g;
    const bf8 bfr = *(const bf8*)(qs + pxd * 256 + ((j ^ (pxd & 7)) * 8));
#pragma unroll
    for (int m = 0; m < 4; ++m) {
      const bf8 afr = *(const bf8*)(mb + (size_t)(m * 16 + c) * 256 + k0 + g * 8);
      oacc[m] = __builtin_amdgcn_mfma_f32_16x16x32_bf16(afr, bfr, oacc[m], 0, 0, 0);
    }
  }

  // ---- Phase E: transpose via LDS (stride 68 f32), emit heads2 bf16
  __syncthreads();
  float* trf = (float*)qs;   // 64 x 68 f32 = 17,408 B
#pragma unroll
  for (int m = 0; m < 4; ++m) {
    float* tp = trf + pxd * 68 + m * 16 + g * 4;
    *(float2*)(tp)     = make_float2(oacc[m][0], oacc[m][1]);
    *(float2*)(tp + 2) = make_float2(oacc[m][2], oacc[m][3]);
  }
  __syncthreads();
  {
    const int px2 = t >> 2, q = t & 3;
    const float* tr = trf + px2 * 68 + q * 16;
    const float4 v0 = *(const float4*)(tr);
    const float4 v1 = *(const float4*)(tr + 4);
    const float4 v2 = *(const float4*)(tr + 8);
    const float4 v3 = *(const float4*)(tr + 12);
    uint4 A, B;
    A.x = pk2(v0.x, v0.y); A.y = pk2(v0.z, v0.w);
    A.z = pk2(v1.x, v1.y); A.w = pk2(v1.z, v1.w);
    B.x = pk2(v2.x, v2.y); B.y = pk2(v2.z, v2.w);
    B.z = pk2(v3.x, v3.y); B.w = pk2(v3.z, v3.w);
    u16* hb = heads2 + ((size_t)bb * L_ + (size_t)y * 64 + px2) * HC + n * 64 + q * 16;
    *(uint4*)(hb)     = A;
    *(uint4*)(hb + 8) = B;
  }
}

// ---------------------------------------------------------------------------
// Final 1x1 conv via MFMA: out[b][o][l] = Wob[o][m] * heads2[b][l][m] + bo[o]
// ---------------------------------------------------------------------------
__global__ __launch_bounds__(256) void k_out_mfma(
    const u16* __restrict__ heads2, const u16* __restrict__ Wob,
    const float* __restrict__ bo, float* __restrict__ out) {
  const int t    = threadIdx.x;
  const int w    = t >> 6;
  const int lane = t & 63;
  const int c    = lane & 15;
  const int g    = lane >> 4;
  const int y    = blockIdx.x;
  const int b    = blockIdx.y;
  const u16* hb = heads2 + ((size_t)b * L_ + (size_t)y * 64) * HC;

  f32x4 acc[4][4];
#pragma unroll
  for (int nn = 0; nn < 4; ++nn)
#pragma unroll
    for (int m = 0; m < 4; ++m) acc[nn][m] = (f32x4){0.f, 0.f, 0.f, 0.f};

  for (int ks = 0; ks < 16; ++ks) {
    const int k0 = ks * 32;
    bf8 bfr[4];
#pragma unroll
    for (int nn = 0; nn < 4; ++nn)
      bfr[nn] = *(const bf8*)(hb + (size_t)(nn * 16 + c) * HC + k0 + g * 8);
#pragma unroll
    for (int m = 0; m < 4; ++m) {
      const bf8 afr = *(const bf8*)(Wob + (size_t)(w * 64 + m * 16 + c) * HC + k0 + g * 8);
#pragma unroll
      for (int nn = 0; nn < 4; ++nn)
        acc[nn][m] = __builtin_amdgcn_mfma_f32_16x16x32_bf16(afr, bfr[nn], acc[nn][m], 0, 0, 0);
    }
  }

  float* ob = out + (size_t)b * OD * L_ + (size_t)y * 64;
#pragma unroll
  for (int m = 0; m < 4; ++m)
#pragma unroll
    for (int r = 0; r < 4; ++r) {
      const int o = w * 64 + m * 16 + g * 4 + r;
      const float bias = bo[o];
#pragma unroll
      for (int nn = 0; nn < 4; ++nn)
        ob[(size_t)o * L_ + nn * 16 + c] = acc[nn][m][r] + bias;
    }
}

// ---------------------------------------------------------------------------
extern "C" void kernel_launch(void* const* d_in, const int* in_sizes, int n_in,
                              void* d_out, int out_size, void* d_ws, size_t ws_size,
                              hipStream_t stream) {
  const float* x    = (const float*)d_in[0];
  const float* Wp   = (const float*)d_in[1];
  const float* bp   = (const float*)d_in[2];
  const float* keyb = (const float*)d_in[3];
  const float* memb = (const float*)d_in[4];
  const float* Wo   = (const float*)d_in[5];
  const float* bo   = (const float*)d_in[6];
  float* out = (float*)d_out;

  // ws layout: Ktb | memt | Wob | Wpb | heads2(all batches)  = 35.4 MB
  // (ws_size >= 67.9 MB established: round-2/3 full-batch branch executed)
  const size_t KTB_B = (size_t)NH * 256 * 288 * 2;   // 1,179,648
  const size_t MEM_B = (size_t)NH * 64 * 256 * 2;    //   262,144
  const size_t WOB_B = (size_t)OD * HC * 2;          //   262,144
  const size_t WPB_B = (size_t)OD * C_ * 2;          //   131,072
  char* ws = (char*)d_ws;
  u16* Ktb    = (u16*)ws;
  u16* memt   = (u16*)(ws + KTB_B);
  u16* Wob    = (u16*)(ws + KTB_B + MEM_B);
  u16* Wpb    = (u16*)(ws + KTB_B + MEM_B + WOB_B);
  u16* heads2 = (u16*)(ws + KTB_B + MEM_B + WOB_B + WPB_B);

  u16* projb = (u16*)d_out;  // bf16 proj [b][c][l] = 16.8 MB; consumed before k_out

  hipLaunchKernelGGL(k_prep,      dim3(5120),      dim3(256), 0, stream,
                     keyb, memb, Wo, Wp, Ktb, memt, Wob, Wpb);
  hipLaunchKernelGGL(k_proj_mfma, dim3(64, 8),     dim3(256), 0, stream,
                     x, Wpb, bp, projb);
  hipLaunchKernelGGL(k_fat,       dim3(64, 8, 8),  dim3(256), 0, stream,
                     projb, Ktb, memt, heads2);
  hipLaunchKernelGGL(k_out_mfma,  dim3(64, 8),     dim3(256), 0, stream,
                     heads2, Wob, bo, out);
}